// Round 3
// baseline (1483.741 us; speedup 1.0000x reference)
//
#include <hip/hip_runtime.h>
#include <stdint.h>

// ---- problem constants (MistralAttention: B=2,S=2048,H=32,KVH=8,D=128) ----
#define NH      32
#define NKVH    8
#define HD      128
#define BATCH   2
#define SEQ     2048
#define HIDDEN  4096
#define KVDIM   1024
#define TOKENS  (BATCH*SEQ)

typedef __bf16 bf16x8 __attribute__((ext_vector_type(8)));
typedef float  f32x4  __attribute__((ext_vector_type(4)));

__device__ __forceinline__ uint16_t f32_to_bf16(float f) {
  union { float f; uint32_t u; } v; v.f = f;
  uint32_t r = v.u + 0x7FFFu + ((v.u >> 16) & 1u);   // RNE
  return (uint16_t)(r >> 16);
}
__device__ __forceinline__ float bf16_to_f32(uint16_t h) {
  union { uint32_t u; float f; } v; v.u = ((uint32_t)h) << 16;
  return v.f;
}
__device__ __forceinline__ bf16x8 ld_frag(const uint16_t* p) {
  return *(const bf16x8*)p;
}
#define MFMA_BF16(a,b,c) __builtin_amdgcn_mfma_f32_16x16x32_bf16((a),(b),(c),0,0,0)

#define NEG_BIG (-1.0e30f)

// ============================================================================
// Staging: global (fp32 OR bf16) -> LDS bf16 tile [128 x 32]
// ============================================================================
template <typename T>
__device__ __forceinline__ void stage_tile(const T* __restrict__ src, uint16_t* dst,
                                           int ldK, int k0, int tid)
{
  if constexpr (sizeof(T) == 4) {           // fp32 source: convert during staging
    #pragma unroll
    for (int i = 0; i < 4; ++i) {
      int gi = tid + i*256;                 // 0..1023 granules of 4 elems
      int r = gi >> 3;                      // 0..127
      int c = (gi & 7) * 4;                 // 0..28
      float4 v = *(const float4*)(src + (size_t)r*ldK + k0 + c);
      uint16_t* d = dst + r*32 + c;
      d[0] = f32_to_bf16(v.x); d[1] = f32_to_bf16(v.y);
      d[2] = f32_to_bf16(v.z); d[3] = f32_to_bf16(v.w);
    }
  } else {                                  // bf16 source: straight 16B copies
    #pragma unroll
    for (int i = 0; i < 2; ++i) {
      int gi = tid + i*256;                 // 0..511 granules of 8 elems
      int r = gi >> 2;
      int c = (gi & 3) * 8;
      *(bf16x8*)&dst[r*32 + c] = *(const bf16x8*)(src + (size_t)r*ldK + k0 + c);
    }
  }
}

__device__ __forceinline__ void store_c(uint16_t* p, float v) { *p = f32_to_bf16(v); }
__device__ __forceinline__ void store_c(float*    p, float v) { *p = v; }

// ============================================================================
// GEMM: C[M,N] = A[M,K] * B[N,K]^T   (128x128 tile, BK=32, bf16 MFMA inside)
// ============================================================================
template <typename TA, typename TB, typename TC>
__device__ __forceinline__ void gemm_body(
    const TA* __restrict__ A, const TB* __restrict__ B,
    TC* __restrict__ C, int m0, int n0, int N, int K)
{
  __shared__ __align__(16) uint16_t As[128*32];
  __shared__ __align__(16) uint16_t Bs[128*32];
  const int tid  = threadIdx.x;
  const int wave = tid >> 6;
  const int lane = tid & 63;
  const int wm = (wave >> 1) * 64;
  const int wn = (wave & 1) * 64;
  const int fr = lane & 15;
  const int fo = (lane >> 4) * 8;
  f32x4 acc[4][4] = {};
  for (int k0 = 0; k0 < K; k0 += 32) {
    __syncthreads();
    stage_tile<TA>(A + (size_t)m0*K, As, K, k0, tid);
    stage_tile<TB>(B + (size_t)n0*K, Bs, K, k0, tid);
    __syncthreads();
    bf16x8 af[4], bfr[4];
    #pragma unroll
    for (int i = 0; i < 4; ++i) af[i]  = ld_frag(&As[(wm + i*16 + fr)*32 + fo]);
    #pragma unroll
    for (int j = 0; j < 4; ++j) bfr[j] = ld_frag(&Bs[(wn + j*16 + fr)*32 + fo]);
    #pragma unroll
    for (int i = 0; i < 4; ++i)
      #pragma unroll
      for (int j = 0; j < 4; ++j)
        acc[i][j] = MFMA_BF16(af[i], bfr[j], acc[i][j]);
  }
  const int cr = (lane >> 4) * 4;      // C layout: col=lane&15, row=(lane>>4)*4+reg
  #pragma unroll
  for (int i = 0; i < 4; ++i)
    #pragma unroll
    for (int j = 0; j < 4; ++j)
      #pragma unroll
      for (int r = 0; r < 4; ++r)
        store_c(&C[(size_t)(m0 + wm + i*16 + cr + r) * N + (n0 + wn + j*16 + fr)],
                acc[i][j][r]);
}

// fused Q/K/V projection: grid.x = 32 (Q) + 8 (K) + 8 (V); fp32 in, bf16 out
__global__ __launch_bounds__(256) void qkv_gemm(
    const float* __restrict__ X,
    const float* __restrict__ Wq, const float* __restrict__ Wk,
    const float* __restrict__ Wv,
    uint16_t* __restrict__ Qo, uint16_t* __restrict__ Ko, uint16_t* __restrict__ Vo)
{
  int bx = blockIdx.x;
  const float* B; uint16_t* C; int n0, N;
  if (bx < 32)      { B = Wq; C = Qo; n0 = bx*128;      N = HIDDEN; }
  else if (bx < 40) { B = Wk; C = Ko; n0 = (bx-32)*128; N = KVDIM;  }
  else              { B = Wv; C = Vo; n0 = (bx-40)*128; N = KVDIM;  }
  gemm_body<float, float, uint16_t>(X, B, C, blockIdx.y*128, n0, N, HIDDEN);
}

// final projection: A = O (bf16), B = Wo (fp32), C = out (fp32)
__global__ __launch_bounds__(256) void out_gemm(
    const uint16_t* __restrict__ A, const float* __restrict__ B,
    float* __restrict__ C, int N, int K)
{
  gemm_body<uint16_t, float, float>(A, B, C, blockIdx.y*128, blockIdx.x*128, N, K);
}

// ============================================================================
// RoPE in-place on Q [TOKENS,HIDDEN] and K [TOKENS,KVDIM] (bf16)
// position = (t % SEQ); inv_freq = 10000^(-j/64) = 10^(-j/16)
// ============================================================================
__global__ __launch_bounds__(256) void rope_kernel(
    uint16_t* __restrict__ Q, uint16_t* __restrict__ K)
{
  int idx = blockIdx.x * 256 + threadIdx.x;
  int j = idx & 63;
  int rest = idx >> 6;
  int h = rest % (NH + NKVH);
  int t = rest / (NH + NKVH);
  float pos = (float)(t % SEQ);
  float inv_freq = __exp10f(-0.0625f * (float)j);
  float ang = pos * inv_freq;
  float s, c;
  __sincosf(ang, &s, &c);
  uint16_t* base = (h < NH) ? (Q + (size_t)t*HIDDEN + h*HD)
                            : (K + (size_t)t*KVDIM + (h-NH)*HD);
  float x1 = bf16_to_f32(base[j]);
  float x2 = bf16_to_f32(base[j+64]);
  base[j]    = f32_to_bf16(x1*c - x2*s);
  base[j+64] = f32_to_bf16(x2*c + x1*s);
}

// ============================================================================
// V transpose: V[TOKENS,KVDIM](bf16) -> Vt[B][KVH][HD][SEQ](bf16)
// ============================================================================
__global__ __launch_bounds__(256) void transpose_v(
    const uint16_t* __restrict__ V, uint16_t* __restrict__ Vt)
{
  __shared__ uint16_t tile[64][66];
  int bh = blockIdx.z;  int b = bh >> 3, h = bh & 7;
  int s0 = blockIdx.x * 64;
  int d0 = blockIdx.y * 64;
  int tx = threadIdx.x & 63;
  int ty = threadIdx.x >> 6;
  const uint16_t* Vp = V + (size_t)b*SEQ*KVDIM + (size_t)h*HD;
  for (int r = ty; r < 64; r += 4)
    tile[r][tx] = Vp[(size_t)(s0 + r)*KVDIM + d0 + tx];
  __syncthreads();
  uint16_t* Vtp = Vt + ((size_t)b*NKVH + h)*HD*SEQ;
  for (int r = ty; r < 64; r += 4)
    Vtp[(size_t)(d0 + r)*SEQ + s0 + tx] = tile[tx][r];
}

// ============================================================================
// Flash attention (causal, GQA): 128-query tile per block, 64-key tiles.
// Q-frags in registers; online softmax in-wave; P via LDS (C->A layout).
// Writes O in-place over Q (each block touches only its own 128-row strip).
// ============================================================================
__global__ __launch_bounds__(256) void flash_attn(
    uint16_t* __restrict__ Q, const uint16_t* __restrict__ K,
    const uint16_t* __restrict__ Vt)
{
  __shared__ __align__(16) uint16_t Ks[64*128];   // [key][d]   16KB
  __shared__ __align__(16) uint16_t Vs[128*64];   // [d][key]   16KB
  __shared__ __align__(16) uint16_t Ps[128*64];   // [q][key]   16KB

  const int tid  = threadIdx.x;
  const int wave = tid >> 6;
  const int lane = tid & 63;
  const int fr = lane & 15;
  const int g  = lane >> 4;
  const int fo = g * 8;
  const int q0 = blockIdx.x * 128;
  const int bh = blockIdx.y;
  const int b = bh >> 5, h = bh & 31;
  const int kvh = h >> 2;   // GQA: 4 Q-heads per KV-head

  uint16_t*       Qp = Q  + (size_t)b*SEQ*HIDDEN + (size_t)h*HD;
  const uint16_t* Kp = K  + (size_t)b*SEQ*KVDIM  + (size_t)kvh*HD;
  const uint16_t* Vp = Vt + ((size_t)b*NKVH + kvh)*HD*SEQ;

  // Q fragments (A-layout) in registers: rows wave*32..+31, d=0..127
  bf16x8 qf[2][4];
  #pragma unroll
  for (int i = 0; i < 2; ++i)
    #pragma unroll
    for (int ks = 0; ks < 4; ++ks)
      qf[i][ks] = ld_frag(Qp + (size_t)(q0 + wave*32 + i*16 + fr)*HIDDEN + ks*32 + fo);

  float m_i[2][4], l_i[2][4];
  f32x4 oacc[2][8] = {};
  #pragma unroll
  for (int i = 0; i < 2; ++i)
    #pragma unroll
    for (int r = 0; r < 4; ++r) { m_i[i][r] = NEG_BIG; l_i[i][r] = 0.f; }

  const int nkt = blockIdx.x * 2 + 2;   // causal: keys up to q0+127
  for (int kt = 0; kt < nkt; ++kt) {
    const int k0 = kt * 64;
    __syncthreads();
    #pragma unroll
    for (int i = 0; i < 4; ++i) {
      int gi = tid + i*256;                    // 0..1023
      int kr = gi >> 4, kc = (gi & 15) * 8;    // Ks: 64 x 128
      *(bf16x8*)&Ks[kr*128 + kc] = *(const bf16x8*)(Kp + (size_t)(k0 + kr)*KVDIM + kc);
      int vr = gi >> 3, vc = (gi & 7) * 8;     // Vs: 128 x 64
      *(bf16x8*)&Vs[vr*64 + vc]  = *(const bf16x8*)(Vp + (size_t)vr*SEQ + k0 + vc);
    }
    __syncthreads();

    // S = Q K^T
    f32x4 sacc[2][4] = {};
    #pragma unroll
    for (int ks = 0; ks < 4; ++ks) {
      bf16x8 bk[4];
      #pragma unroll
      for (int j = 0; j < 4; ++j) bk[j] = ld_frag(&Ks[(j*16 + fr)*128 + ks*32 + fo]);
      #pragma unroll
      for (int i = 0; i < 2; ++i)
        #pragma unroll
        for (int j = 0; j < 4; ++j)
          sacc[i][j] = MFMA_BF16(qf[i][ks], bk[j], sacc[i][j]);
    }

    // scale + causal mask + online softmax
    const bool diag = (k0 + 64 > q0);
    #pragma unroll
    for (int i = 0; i < 2; ++i)
      #pragma unroll
      for (int r = 0; r < 4; ++r) {
        float vals[4];
        #pragma unroll
        for (int j = 0; j < 4; ++j) {
          float v = sacc[i][j][r] * 0.08838834764831845f;  // 1/sqrt(128)
          if (diag) {
            int qrow = q0 + wave*32 + i*16 + g*4 + r;
            int kcol = k0 + j*16 + fr;
            if (kcol > qrow) v = NEG_BIG;
          }
          vals[j] = v;
        }
        float mt = fmaxf(fmaxf(vals[0], vals[1]), fmaxf(vals[2], vals[3]));
        #pragma unroll
        for (int off = 1; off < 16; off <<= 1) mt = fmaxf(mt, __shfl_xor(mt, off, 64));
        float mn = fmaxf(m_i[i][r], mt);
        float alpha = __expf(fminf(m_i[i][r] - mn, 0.f));
        float lt = 0.f;
        #pragma unroll
        for (int j = 0; j < 4; ++j) {
          float p = __expf(fminf(vals[j] - mn, 0.f));
          sacc[i][j][r] = p;
          lt += p;
        }
        #pragma unroll
        for (int off = 1; off < 16; off <<= 1) lt += __shfl_xor(lt, off, 64);
        m_i[i][r] = mn;
        l_i[i][r] = l_i[i][r]*alpha + lt;
        #pragma unroll
        for (int n = 0; n < 8; ++n) oacc[i][n][r] *= alpha;
      }

    // P (C-layout) -> LDS -> A-layout
    #pragma unroll
    for (int i = 0; i < 2; ++i)
      #pragma unroll
      for (int j = 0; j < 4; ++j)
        #pragma unroll
        for (int r = 0; r < 4; ++r)
          Ps[(wave*32 + i*16 + g*4 + r)*64 + j*16 + fr] = f32_to_bf16(sacc[i][j][r]);
    __syncthreads();

    // O += P * V
    #pragma unroll
    for (int ks = 0; ks < 2; ++ks) {
      bf16x8 ap[2], bv[8];
      #pragma unroll
      for (int i = 0; i < 2; ++i)
        ap[i] = ld_frag(&Ps[(wave*32 + i*16 + fr)*64 + ks*32 + fo]);
      #pragma unroll
      for (int n = 0; n < 8; ++n)
        bv[n] = ld_frag(&Vs[(n*16 + fr)*64 + ks*32 + fo]);
      #pragma unroll
      for (int i = 0; i < 2; ++i)
        #pragma unroll
        for (int n = 0; n < 8; ++n)
          oacc[i][n] = MFMA_BF16(ap[i], bv[n], oacc[i][n]);
    }
  }

  // epilogue: O over Q in-place
  #pragma unroll
  for (int i = 0; i < 2; ++i)
    #pragma unroll
    for (int r = 0; r < 4; ++r) {
      float inv_l = 1.0f / l_i[i][r];
      int qrow = q0 + wave*32 + i*16 + g*4 + r;
      #pragma unroll
      for (int n = 0; n < 8; ++n)
        Qp[(size_t)qrow*HIDDEN + n*16 + fr] = f32_to_bf16(oacc[i][n][r] * inv_l);
    }
}

// ============================================================================
extern "C" void kernel_launch(void* const* d_in, const int* in_sizes, int n_in,
                              void* d_out, int out_size, void* d_ws, size_t ws_size,
                              hipStream_t stream)
{
  (void)in_sizes; (void)n_in; (void)out_size; (void)ws_size;
  const float* hidden = (const float*)d_in[0];   // fp32 per reference
  // d_in[1] = position_ids (int32): deterministically arange(S) per batch; unused.
  const float* wq = (const float*)d_in[2];
  const float* wk = (const float*)d_in[3];
  const float* wv = (const float*)d_in[4];
  const float* wo = (const float*)d_in[5];
  float* out = (float*)d_out;                    // fp32 per reference output

  // workspace (bf16 intermediates): Q/O(32MB) K(8MB) V(8MB) Vt(8MB) = 56MB
  uint16_t* Qb = (uint16_t*)d_ws;
  uint16_t* Kb = Qb + (size_t)TOKENS*HIDDEN;
  uint16_t* Vb = Kb + (size_t)TOKENS*KVDIM;
  uint16_t* Vt = Vb + (size_t)TOKENS*KVDIM;

  dim3 blk(256);
  qkv_gemm<<<dim3(48, TOKENS/128), blk, 0, stream>>>(hidden, wq, wk, wv, Qb, Kb, Vb);
  rope_kernel<<<dim3(TOKENS*(NH+NKVH)*64/256), blk, 0, stream>>>(Qb, Kb);
  transpose_v<<<dim3(SEQ/64, HD/64, BATCH*NKVH), blk, 0, stream>>>(Vb, Vt);
  flash_attn<<<dim3(SEQ/128, BATCH*NH), blk, 0, stream>>>(Qb, Kb, Vt);
  out_gemm<<<dim3(HIDDEN/128, TOKENS/128), blk, 0, stream>>>(Qb, wo, out, HIDDEN, HIDDEN);
}

// Round 4
// 907.680 us; speedup vs baseline: 1.6347x; 1.6347x over previous
//
#include <hip/hip_runtime.h>
#include <stdint.h>

// ---- problem constants (MistralAttention: B=2,S=2048,H=32,KVH=8,D=128) ----
#define NH      32
#define NKVH    8
#define HD      128
#define BATCH   2
#define SEQ     2048
#define HIDDEN  4096
#define KVDIM   1024
#define TOKENS  (BATCH*SEQ)

typedef __bf16 bf16x8 __attribute__((ext_vector_type(8)));
typedef float  f32x4  __attribute__((ext_vector_type(4)));

__device__ __forceinline__ uint16_t f32_to_bf16(float f) {
  union { float f; uint32_t u; } v; v.f = f;
  uint32_t r = v.u + 0x7FFFu + ((v.u >> 16) & 1u);   // RNE
  return (uint16_t)(r >> 16);
}
__device__ __forceinline__ float bf16_to_f32(uint16_t h) {
  union { uint32_t u; float f; } v; v.u = ((uint32_t)h) << 16;
  return v.f;
}
__device__ __forceinline__ bf16x8 ld_frag(const uint16_t* p) {
  return *(const bf16x8*)p;
}
#define MFMA_BF16(a,b,c) __builtin_amdgcn_mfma_f32_16x16x32_bf16((a),(b),(c),0,0,0)
#define NEG_BIG (-1.0e30f)

typedef __attribute__((address_space(1))) void as1_void;
typedef __attribute__((address_space(3))) void as3_void;
// async global->LDS, 16B per lane; LDS dest = wave-uniform base + lane*16
__device__ __forceinline__ void gload_lds16(const void* g, void* l) {
  __builtin_amdgcn_global_load_lds((as1_void*)g, (as3_void*)l, 16, 0, 0);
}

// ============================================================================
// fp32 -> bf16 conversion (one-time, 8 elems/thread)
// ============================================================================
__global__ __launch_bounds__(256) void cvt_f32_bf16(
    const float* __restrict__ s, uint16_t* __restrict__ d, int n8)
{
  int i = blockIdx.x * 256 + threadIdx.x;
  if (i < n8) {
    const float4* sp = (const float4*)s + 2*(size_t)i;
    float4 a = sp[0], b = sp[1];
    union { uint16_t u[8]; uint4 v; } o;
    o.u[0]=f32_to_bf16(a.x); o.u[1]=f32_to_bf16(a.y);
    o.u[2]=f32_to_bf16(a.z); o.u[3]=f32_to_bf16(a.w);
    o.u[4]=f32_to_bf16(b.x); o.u[5]=f32_to_bf16(b.y);
    o.u[6]=f32_to_bf16(b.z); o.u[7]=f32_to_bf16(b.w);
    ((uint4*)d)[i] = o.v;
  }
}

// ============================================================================
// GEMM (m97 structure): C[M,N] = A[M,K](bf16) * B[N,K]^T(bf16)
// 128x128 tile, BK=32, global_load_lds width-16 staging
// ============================================================================
__device__ __forceinline__ void store_c(uint16_t* p, float v) { *p = f32_to_bf16(v); }
__device__ __forceinline__ void store_c(float*    p, float v) { *p = v; }

template <typename TC>
__device__ __forceinline__ void gemm_body(
    const uint16_t* __restrict__ A, const uint16_t* __restrict__ B,
    TC* __restrict__ C, int m0, int n0, int N, int K)
{
  __shared__ __align__(16) uint16_t As[128*32];
  __shared__ __align__(16) uint16_t Bs[128*32];
  const int tid  = threadIdx.x;
  const int wave = tid >> 6;
  const int lane = tid & 63;
  const int wm = (wave >> 1) * 64;
  const int wn = (wave & 1) * 64;
  const int srow = lane >> 2;          // staging: 4 lanes x 16B per 64B row
  const int scol = (lane & 3) * 8;
  const uint16_t* Ap = A + (size_t)(m0 + wave*16 + srow) * K + scol;
  const uint16_t* Bp = B + (size_t)(n0 + wave*16 + srow) * K + scol;
  uint16_t* AsW = &As[(wave*16)*32];   // wave-uniform LDS base
  uint16_t* BsW = &Bs[(wave*16)*32];
  const int fr = lane & 15;
  const int fo = (lane >> 4) * 8;
  f32x4 acc[4][4] = {};
  for (int k0 = 0; k0 < K; k0 += 32) {
    __syncthreads();
    gload_lds16(Ap + k0,                AsW);
    gload_lds16(Ap + k0 + (size_t)64*K, AsW + 64*32);
    gload_lds16(Bp + k0,                BsW);
    gload_lds16(Bp + k0 + (size_t)64*K, BsW + 64*32);
    __syncthreads();
    bf16x8 af[4], bfr[4];
    #pragma unroll
    for (int i = 0; i < 4; ++i) af[i]  = ld_frag(&As[(wm + i*16 + fr)*32 + fo]);
    #pragma unroll
    for (int j = 0; j < 4; ++j) bfr[j] = ld_frag(&Bs[(wn + j*16 + fr)*32 + fo]);
    #pragma unroll
    for (int i = 0; i < 4; ++i)
      #pragma unroll
      for (int j = 0; j < 4; ++j)
        acc[i][j] = MFMA_BF16(af[i], bfr[j], acc[i][j]);
  }
  const int cr = (lane >> 4) * 4;      // C layout: col=lane&15, row=(lane>>4)*4+reg
  #pragma unroll
  for (int i = 0; i < 4; ++i)
    #pragma unroll
    for (int j = 0; j < 4; ++j)
      #pragma unroll
      for (int r = 0; r < 4; ++r)
        store_c(&C[(size_t)(m0 + wm + i*16 + cr + r) * N + (n0 + wn + j*16 + fr)],
                acc[i][j][r]);
}

// fused Q/K/V projection: grid.x = 32 (Q) + 8 (K) + 8 (V)
__global__ __launch_bounds__(256) void qkv_gemm(
    const uint16_t* __restrict__ X,
    const uint16_t* __restrict__ Wq, const uint16_t* __restrict__ Wk,
    const uint16_t* __restrict__ Wv,
    uint16_t* __restrict__ Qo, uint16_t* __restrict__ Ko, uint16_t* __restrict__ Vo)
{
  int bx = blockIdx.x;
  const uint16_t* B; uint16_t* C; int n0, N;
  if (bx < 32)      { B = Wq; C = Qo; n0 = bx*128;      N = HIDDEN; }
  else if (bx < 40) { B = Wk; C = Ko; n0 = (bx-32)*128; N = KVDIM;  }
  else              { B = Wv; C = Vo; n0 = (bx-40)*128; N = KVDIM;  }
  gemm_body<uint16_t>(X, B, C, blockIdx.y*128, n0, N, HIDDEN);
}

// final projection: C fp32 to d_out
__global__ __launch_bounds__(256) void out_gemm(
    const uint16_t* __restrict__ A, const uint16_t* __restrict__ B,
    float* __restrict__ C, int N, int K)
{
  gemm_body<float>(A, B, C, blockIdx.y*128, blockIdx.x*128, N, K);
}

// ============================================================================
// RoPE in-place on Q [TOKENS,HIDDEN] and K [TOKENS,KVDIM] (bf16)
// position = (t % SEQ); inv_freq = 10000^(-j/64) = 10^(-j/16)
// ============================================================================
__global__ __launch_bounds__(256) void rope_kernel(
    uint16_t* __restrict__ Q, uint16_t* __restrict__ K)
{
  int idx = blockIdx.x * 256 + threadIdx.x;
  int j = idx & 63;
  int rest = idx >> 6;
  int h = rest % (NH + NKVH);
  int t = rest / (NH + NKVH);
  float pos = (float)(t % SEQ);
  float inv_freq = __exp10f(-0.0625f * (float)j);
  float ang = pos * inv_freq;
  float s, c;
  __sincosf(ang, &s, &c);
  uint16_t* base = (h < NH) ? (Q + (size_t)t*HIDDEN + h*HD)
                            : (K + (size_t)t*KVDIM + (h-NH)*HD);
  float x1 = bf16_to_f32(base[j]);
  float x2 = bf16_to_f32(base[j+64]);
  base[j]    = f32_to_bf16(x1*c - x2*s);
  base[j+64] = f32_to_bf16(x2*c + x1*s);
}

// ============================================================================
// V transpose: V[TOKENS,KVDIM](bf16) -> Vt[B][KVH][HD][SEQ](bf16)
// ============================================================================
__global__ __launch_bounds__(256) void transpose_v(
    const uint16_t* __restrict__ V, uint16_t* __restrict__ Vt)
{
  __shared__ uint16_t tile[64][66];
  int bh = blockIdx.z;  int b = bh >> 3, h = bh & 7;
  int s0 = blockIdx.x * 64;
  int d0 = blockIdx.y * 64;
  int tx = threadIdx.x & 63;
  int ty = threadIdx.x >> 6;
  const uint16_t* Vp = V + (size_t)b*SEQ*KVDIM + (size_t)h*HD;
  for (int r = ty; r < 64; r += 4)
    tile[r][tx] = Vp[(size_t)(s0 + r)*KVDIM + d0 + tx];
  __syncthreads();
  uint16_t* Vtp = Vt + ((size_t)b*NKVH + h)*HD*SEQ;
  for (int r = ty; r < 64; r += 4)
    Vtp[(size_t)(d0 + r)*SEQ + s0 + tx] = tile[tx][r];
}

// ============================================================================
// Flash attention (causal, GQA): TWO 128-query tiles per block (bx, 15-bx)
// for perfect causal load balance (36 k-tile iters per block).
// Padded LDS strides kill the 16-way bank conflicts.
// Writes O in-place over Q.
// ============================================================================
#define KSTR 136   // Ks row stride (128 cols + 8 pad)
#define VSTR 72    // Vs/Ps row stride (64 cols + 8 pad)

__global__ __launch_bounds__(256) void flash_attn(
    uint16_t* __restrict__ Q, const uint16_t* __restrict__ K,
    const uint16_t* __restrict__ Vt)
{
  __shared__ __align__(16) uint16_t Ks[64*KSTR];    // 17.0 KB
  __shared__ __align__(16) uint16_t Vs[128*VSTR];   // 18.0 KB
  __shared__ __align__(16) uint16_t Ps[128*VSTR];   // 18.0 KB

  const int tid  = threadIdx.x;
  const int wave = tid >> 6;
  const int lane = tid & 63;
  const int fr = lane & 15;
  const int g  = lane >> 4;
  const int fo = g * 8;
  const int bh = blockIdx.y;
  const int b = bh >> 5, h = bh & 31;
  const int kvh = h >> 2;   // GQA: 4 Q-heads per KV-head

  uint16_t*       Qh = Q  + (size_t)b*SEQ*HIDDEN + (size_t)h*HD;
  const uint16_t* Kp = K  + (size_t)b*SEQ*KVDIM  + (size_t)kvh*HD;
  const uint16_t* Vp = Vt + ((size_t)b*NKVH + kvh)*HD*SEQ;

  #pragma unroll
  for (int pass = 0; pass < 2; ++pass) {
    const int qt = pass ? (15 - (int)blockIdx.x) : (int)blockIdx.x;
    const int q0 = qt * 128;

    // Q fragments (A-layout) in registers: rows wave*32..+31, d=0..127
    bf16x8 qf[2][4];
    #pragma unroll
    for (int i = 0; i < 2; ++i)
      #pragma unroll
      for (int ks = 0; ks < 4; ++ks)
        qf[i][ks] = ld_frag(Qh + (size_t)(q0 + wave*32 + i*16 + fr)*HIDDEN + ks*32 + fo);

    float m_i[2][4], l_i[2][4];
    f32x4 oacc[2][8] = {};
    #pragma unroll
    for (int i = 0; i < 2; ++i)
      #pragma unroll
      for (int r = 0; r < 4; ++r) { m_i[i][r] = NEG_BIG; l_i[i][r] = 0.f; }

    const int nkt = qt * 2 + 2;   // causal: keys up to q0+127
    for (int kt = 0; kt < nkt; ++kt) {
      const int k0 = kt * 64;
      __syncthreads();
      #pragma unroll
      for (int i = 0; i < 4; ++i) {
        int gi = tid + i*256;                    // 0..1023
        int kr = gi >> 4, kc = (gi & 15) * 8;    // Ks: 64 x 128
        *(bf16x8*)&Ks[kr*KSTR + kc] = *(const bf16x8*)(Kp + (size_t)(k0 + kr)*KVDIM + kc);
        int vr = gi >> 3, vc = (gi & 7) * 8;     // Vs: 128 x 64
        *(bf16x8*)&Vs[vr*VSTR + vc] = *(const bf16x8*)(Vp + (size_t)vr*SEQ + k0 + vc);
      }
      __syncthreads();

      // S = Q K^T
      f32x4 sacc[2][4] = {};
      #pragma unroll
      for (int ks = 0; ks < 4; ++ks) {
        bf16x8 bk[4];
        #pragma unroll
        for (int j = 0; j < 4; ++j) bk[j] = ld_frag(&Ks[(j*16 + fr)*KSTR + ks*32 + fo]);
        #pragma unroll
        for (int i = 0; i < 2; ++i)
          #pragma unroll
          for (int j = 0; j < 4; ++j)
            sacc[i][j] = MFMA_BF16(qf[i][ks], bk[j], sacc[i][j]);
      }

      // scale + causal mask + online softmax (row lives in 16 fr-lanes)
      const bool diag = (k0 + 64 > q0);
      #pragma unroll
      for (int i = 0; i < 2; ++i)
        #pragma unroll
        for (int r = 0; r < 4; ++r) {
          float vals[4];
          #pragma unroll
          for (int j = 0; j < 4; ++j) {
            float v = sacc[i][j][r] * 0.08838834764831845f;  // 1/sqrt(128)
            if (diag) {
              int qrow = q0 + wave*32 + i*16 + g*4 + r;
              int kcol = k0 + j*16 + fr;
              if (kcol > qrow) v = NEG_BIG;
            }
            vals[j] = v;
          }
          float mt = fmaxf(fmaxf(vals[0], vals[1]), fmaxf(vals[2], vals[3]));
          #pragma unroll
          for (int off = 1; off < 16; off <<= 1) mt = fmaxf(mt, __shfl_xor(mt, off, 64));
          float mn = fmaxf(m_i[i][r], mt);
          float alpha = __expf(fminf(m_i[i][r] - mn, 0.f));
          float lt = 0.f;
          #pragma unroll
          for (int j = 0; j < 4; ++j) {
            float p = __expf(fminf(vals[j] - mn, 0.f));
            sacc[i][j][r] = p;
            lt += p;
          }
          #pragma unroll
          for (int off = 1; off < 16; off <<= 1) lt += __shfl_xor(lt, off, 64);
          m_i[i][r] = mn;
          l_i[i][r] = l_i[i][r]*alpha + lt;
          #pragma unroll
          for (int n = 0; n < 8; ++n) oacc[i][n][r] *= alpha;
        }

      // P (C-layout) -> LDS -> A-layout
      #pragma unroll
      for (int i = 0; i < 2; ++i)
        #pragma unroll
        for (int j = 0; j < 4; ++j)
          #pragma unroll
          for (int r = 0; r < 4; ++r)
            Ps[(wave*32 + i*16 + g*4 + r)*VSTR + j*16 + fr] = f32_to_bf16(sacc[i][j][r]);
      __syncthreads();

      // O += P * V
      #pragma unroll
      for (int ks = 0; ks < 2; ++ks) {
        bf16x8 ap[2], bv[8];
        #pragma unroll
        for (int i = 0; i < 2; ++i)
          ap[i] = ld_frag(&Ps[(wave*32 + i*16 + fr)*VSTR + ks*32 + fo]);
        #pragma unroll
        for (int n = 0; n < 8; ++n)
          bv[n] = ld_frag(&Vs[(n*16 + fr)*VSTR + ks*32 + fo]);
        #pragma unroll
        for (int i = 0; i < 2; ++i)
          #pragma unroll
          for (int n = 0; n < 8; ++n)
            oacc[i][n] = MFMA_BF16(ap[i], bv[n], oacc[i][n]);
      }
    }

    // epilogue: O over Q in-place (this block's strip only)
    #pragma unroll
    for (int i = 0; i < 2; ++i)
      #pragma unroll
      for (int r = 0; r < 4; ++r) {
        float inv_l = 1.0f / l_i[i][r];
        int qrow = q0 + wave*32 + i*16 + g*4 + r;
        #pragma unroll
        for (int n = 0; n < 8; ++n)
          Qh[(size_t)qrow*HIDDEN + n*16 + fr] = f32_to_bf16(oacc[i][n][r] * inv_l);
      }
    __syncthreads();   // LDS safe before next pass
  }
}

// ============================================================================
extern "C" void kernel_launch(void* const* d_in, const int* in_sizes, int n_in,
                              void* d_out, int out_size, void* d_ws, size_t ws_size,
                              hipStream_t stream)
{
  (void)in_sizes; (void)n_in; (void)out_size; (void)ws_size;
  const float* hidden = (const float*)d_in[0];   // fp32 per reference
  const float* wq = (const float*)d_in[2];
  const float* wk = (const float*)d_in[3];
  const float* wv = (const float*)d_in[4];
  const float* wo = (const float*)d_in[5];
  float* out = (float*)d_out;                    // fp32 per reference output

  // bf16 workspace with aliasing (~134 MB):
  //  R0: Xb (until qkv) -> Wob (from after qkv)
  //  R1: Wqb (until qkv) -> Vt (from transpose_v)
  //  R2: Wkb, R3: Wvb, Qb (O in-place), Kb, Vb
  uint16_t* R0 = (uint16_t*)d_ws;                         // 16.78M elems
  uint16_t* R1 = R0 + (size_t)HIDDEN*HIDDEN;              // 16.78M
  uint16_t* R2 = R1 + (size_t)HIDDEN*HIDDEN;              //  4.19M
  uint16_t* R3 = R2 + (size_t)KVDIM*HIDDEN;               //  4.19M
  uint16_t* Qb = R3 + (size_t)KVDIM*HIDDEN;               // 16.78M
  uint16_t* Kb = Qb + (size_t)TOKENS*HIDDEN;              //  4.19M
  uint16_t* Vb = Kb + (size_t)TOKENS*KVDIM;               //  4.19M

  dim3 blk(256);
  const int n8_big = HIDDEN*HIDDEN/8;     // X, Wq, Wo
  const int n8_kv  = KVDIM*HIDDEN/8;      // Wk, Wv
  cvt_f32_bf16<<<dim3((n8_big+255)/256), blk, 0, stream>>>(hidden, R0, n8_big);
  cvt_f32_bf16<<<dim3((n8_big+255)/256), blk, 0, stream>>>(wq,     R1, n8_big);
  cvt_f32_bf16<<<dim3((n8_kv +255)/256), blk, 0, stream>>>(wk,     R2, n8_kv);
  cvt_f32_bf16<<<dim3((n8_kv +255)/256), blk, 0, stream>>>(wv,     R3, n8_kv);

  qkv_gemm<<<dim3(48, TOKENS/128), blk, 0, stream>>>(R0, R1, R2, R3, Qb, Kb, Vb);
  rope_kernel<<<dim3(TOKENS*(NH+NKVH)*64/256), blk, 0, stream>>>(Qb, Kb);

  cvt_f32_bf16<<<dim3((n8_big+255)/256), blk, 0, stream>>>(wo, R0, n8_big); // Wo -> R0 (Xb dead)
  transpose_v<<<dim3(SEQ/64, HD/64, BATCH*NKVH), blk, 0, stream>>>(Vb, R1); // Vt -> R1 (Wq dead)

  flash_attn<<<dim3(8, BATCH*NH), blk, 0, stream>>>(Qb, Kb, R1);
  out_gemm<<<dim3(HIDDEN/128, TOKENS/128), blk, 0, stream>>>(Qb, R0, out, HIDDEN, HIDDEN);
}

// Round 5
// 851.601 us; speedup vs baseline: 1.7423x; 1.0659x over previous
//
#include <hip/hip_runtime.h>
#include <stdint.h>

// ---- problem constants (MistralAttention: B=2,S=2048,H=32,KVH=8,D=128) ----
#define NH      32
#define NKVH    8
#define HD      128
#define BATCH   2
#define SEQ     2048
#define HIDDEN  4096
#define KVDIM   1024
#define TOKENS  (BATCH*SEQ)

typedef __bf16 bf16x8 __attribute__((ext_vector_type(8)));
typedef float  f32x4  __attribute__((ext_vector_type(4)));

__device__ __forceinline__ uint16_t f32_to_bf16(float f) {
  union { float f; uint32_t u; } v; v.f = f;
  uint32_t r = v.u + 0x7FFFu + ((v.u >> 16) & 1u);   // RNE
  return (uint16_t)(r >> 16);
}
__device__ __forceinline__ float bf16_to_f32(uint16_t h) {
  union { uint32_t u; float f; } v; v.u = ((uint32_t)h) << 16;
  return v.f;
}
__device__ __forceinline__ bf16x8 ld_frag(const uint16_t* p) {
  return *(const bf16x8*)p;
}
#define MFMA_BF16(a,b,c) __builtin_amdgcn_mfma_f32_16x16x32_bf16((a),(b),(c),0,0,0)
#define NEG_BIG (-1.0e30f)

typedef __attribute__((address_space(1))) void as1_void;
typedef __attribute__((address_space(3))) void as3_void;
// async global->LDS, 16B per lane; LDS dest = wave-uniform base + lane*16
__device__ __forceinline__ void gload_lds16(const void* g, void* l) {
  __builtin_amdgcn_global_load_lds((as1_void*)g, (as3_void*)l, 16, 0, 0);
}

// ============================================================================
// fp32 -> bf16 conversion; single kernel for X, Wq, Wk, Wv (exact grids)
// ============================================================================
__device__ __forceinline__ void cvt8(const float* __restrict__ s,
                                     uint16_t* __restrict__ d, size_t i) {
  const float4* sp = (const float4*)s + 2*i;
  float4 a = sp[0], b = sp[1];
  union { uint16_t u[8]; uint4 v; } o;
  o.u[0]=f32_to_bf16(a.x); o.u[1]=f32_to_bf16(a.y);
  o.u[2]=f32_to_bf16(a.z); o.u[3]=f32_to_bf16(a.w);
  o.u[4]=f32_to_bf16(b.x); o.u[5]=f32_to_bf16(b.y);
  o.u[6]=f32_to_bf16(b.z); o.u[7]=f32_to_bf16(b.w);
  ((uint4*)d)[i] = o.v;
}

// grid.x = 8192 + 8192 + 2048 + 2048 = 20480 blocks of 256 (exact, no tails)
__global__ __launch_bounds__(256) void cvt_all(
    const float* __restrict__ X,  const float* __restrict__ Wq,
    const float* __restrict__ Wk, const float* __restrict__ Wv,
    uint16_t* __restrict__ R0, uint16_t* __restrict__ R1,
    uint16_t* __restrict__ R2, uint16_t* __restrict__ R3)
{
  int blk = blockIdx.x;
  const float* s; uint16_t* d; int b0;
  if (blk < 8192)       { s = X;  d = R0; b0 = 0; }
  else if (blk < 16384) { s = Wq; d = R1; b0 = 8192; }
  else if (blk < 18432) { s = Wk; d = R2; b0 = 16384; }
  else                  { s = Wv; d = R3; b0 = 18432; }
  cvt8(s, d, (size_t)(blk - b0)*256 + threadIdx.x);
}

__global__ __launch_bounds__(256) void cvt_one(
    const float* __restrict__ s, uint16_t* __restrict__ d)
{
  cvt8(s, d, (size_t)blockIdx.x*256 + threadIdx.x);
}

// ============================================================================
// GEMM (m97 structure): C[M,N] = A[M,K](bf16) * B[N,K]^T(bf16)
// 128x128 tile, BK=32, global_load_lds width-16 staging
// ============================================================================
__device__ __forceinline__ void store_c(uint16_t* p, float v) { *p = f32_to_bf16(v); }
__device__ __forceinline__ void store_c(float*    p, float v) { *p = v; }

template <typename TC>
__device__ __forceinline__ void gemm_body(
    const uint16_t* __restrict__ A, const uint16_t* __restrict__ B,
    TC* __restrict__ C, int m0, int n0, int N, int K)
{
  __shared__ __align__(16) uint16_t As[128*32];
  __shared__ __align__(16) uint16_t Bs[128*32];
  const int tid  = threadIdx.x;
  const int wave = tid >> 6;
  const int lane = tid & 63;
  const int wm = (wave >> 1) * 64;
  const int wn = (wave & 1) * 64;
  const int srow = lane >> 2;          // staging: 4 lanes x 16B per 64B row
  const int scol = (lane & 3) * 8;
  const uint16_t* Ap = A + (size_t)(m0 + wave*16 + srow) * K + scol;
  const uint16_t* Bp = B + (size_t)(n0 + wave*16 + srow) * K + scol;
  uint16_t* AsW = &As[(wave*16)*32];   // wave-uniform LDS base
  uint16_t* BsW = &Bs[(wave*16)*32];
  const int fr = lane & 15;
  const int fo = (lane >> 4) * 8;
  f32x4 acc[4][4] = {};
  for (int k0 = 0; k0 < K; k0 += 32) {
    __syncthreads();
    gload_lds16(Ap + k0,                AsW);
    gload_lds16(Ap + k0 + (size_t)64*K, AsW + 64*32);
    gload_lds16(Bp + k0,                BsW);
    gload_lds16(Bp + k0 + (size_t)64*K, BsW + 64*32);
    __syncthreads();
    bf16x8 af[4], bfr[4];
    #pragma unroll
    for (int i = 0; i < 4; ++i) af[i]  = ld_frag(&As[(wm + i*16 + fr)*32 + fo]);
    #pragma unroll
    for (int j = 0; j < 4; ++j) bfr[j] = ld_frag(&Bs[(wn + j*16 + fr)*32 + fo]);
    #pragma unroll
    for (int i = 0; i < 4; ++i)
      #pragma unroll
      for (int j = 0; j < 4; ++j)
        acc[i][j] = MFMA_BF16(af[i], bfr[j], acc[i][j]);
  }
  const int cr = (lane >> 4) * 4;      // C layout: col=lane&15, row=(lane>>4)*4+reg
  #pragma unroll
  for (int i = 0; i < 4; ++i)
    #pragma unroll
    for (int j = 0; j < 4; ++j)
      #pragma unroll
      for (int r = 0; r < 4; ++r)
        store_c(&C[(size_t)(m0 + wm + i*16 + cr + r) * N + (n0 + wn + j*16 + fr)],
                acc[i][j][r]);
}

// fused Q/K/V projection: grid.x = 32 (Q) + 8 (K) + 8 (V)
__global__ __launch_bounds__(256) void qkv_gemm(
    const uint16_t* __restrict__ X,
    const uint16_t* __restrict__ Wq, const uint16_t* __restrict__ Wk,
    const uint16_t* __restrict__ Wv,
    uint16_t* __restrict__ Qo, uint16_t* __restrict__ Ko, uint16_t* __restrict__ Vo)
{
  int bx = blockIdx.x;
  const uint16_t* B; uint16_t* C; int n0, N;
  if (bx < 32)      { B = Wq; C = Qo; n0 = bx*128;      N = HIDDEN; }
  else if (bx < 40) { B = Wk; C = Ko; n0 = (bx-32)*128; N = KVDIM;  }
  else              { B = Wv; C = Vo; n0 = (bx-40)*128; N = KVDIM;  }
  gemm_body<uint16_t>(X, B, C, blockIdx.y*128, n0, N, HIDDEN);
}

// final projection: C fp32 to d_out
__global__ __launch_bounds__(256) void out_gemm(
    const uint16_t* __restrict__ A, const uint16_t* __restrict__ B,
    float* __restrict__ C, int N, int K)
{
  gemm_body<float>(A, B, C, blockIdx.y*128, blockIdx.x*128, N, K);
}

// ============================================================================
// RoPE in-place on Q [TOKENS,HIDDEN] and K [TOKENS,KVDIM] (bf16)
// position = (t % SEQ); inv_freq = 10000^(-j/64) = 10^(-j/16)
// ============================================================================
__global__ __launch_bounds__(256) void rope_kernel(
    uint16_t* __restrict__ Q, uint16_t* __restrict__ K)
{
  int idx = blockIdx.x * 256 + threadIdx.x;
  int j = idx & 63;
  int rest = idx >> 6;
  int h = rest % (NH + NKVH);
  int t = rest / (NH + NKVH);
  float pos = (float)(t % SEQ);
  float inv_freq = __exp10f(-0.0625f * (float)j);
  float ang = pos * inv_freq;
  float s, c;
  __sincosf(ang, &s, &c);
  uint16_t* base = (h < NH) ? (Q + (size_t)t*HIDDEN + h*HD)
                            : (K + (size_t)t*KVDIM + (h-NH)*HD);
  float x1 = bf16_to_f32(base[j]);
  float x2 = bf16_to_f32(base[j+64]);
  base[j]    = f32_to_bf16(x1*c - x2*s);
  base[j+64] = f32_to_bf16(x2*c + x1*s);
}

// ============================================================================
// V transpose: V[TOKENS,KVDIM](bf16) -> Vt[B][KVH][HD][SEQ](bf16)
// ============================================================================
__global__ __launch_bounds__(256) void transpose_v(
    const uint16_t* __restrict__ V, uint16_t* __restrict__ Vt)
{
  __shared__ uint16_t tile[64][66];
  int bh = blockIdx.z;  int b = bh >> 3, h = bh & 7;
  int s0 = blockIdx.x * 64;
  int d0 = blockIdx.y * 64;
  int tx = threadIdx.x & 63;
  int ty = threadIdx.x >> 6;
  const uint16_t* Vp = V + (size_t)b*SEQ*KVDIM + (size_t)h*HD;
  for (int r = ty; r < 64; r += 4)
    tile[r][tx] = Vp[(size_t)(s0 + r)*KVDIM + d0 + tx];
  __syncthreads();
  uint16_t* Vtp = Vt + ((size_t)b*NKVH + h)*HD*SEQ;
  for (int r = ty; r < 64; r += 4)
    Vtp[(size_t)(d0 + r)*SEQ + s0 + tx] = tile[tx][r];
}

// ============================================================================
// Flash attention (causal, GQA), occupancy-optimized:
//  - BQ=64 (each of 4 waves owns 16 q-rows) -> low VGPR -> 4 waves/SIMD
//  - Ps aliased into Ks (dead after QK^T) -> 35.8 KB LDS -> 4 blocks/CU
//  - q-tile pairing (bx, 31-bx): every block runs exactly 33 k-iterations
//  - 3 syncthreads per 64-key tile; PV reads only the wave's own Ps strip
//  - O written in-place over Q (each Q row is read only by its owning block)
// ============================================================================
#define KSTR 136   // Ks row stride (128 cols + 8 pad)
#define VSTR 72    // Vs/Ps row stride (64 cols + 8 pad)

__global__ __launch_bounds__(256, 4) void flash_attn(
    uint16_t* __restrict__ Q, const uint16_t* __restrict__ K,
    const uint16_t* __restrict__ Vt)
{
  __shared__ __align__(16) uint16_t Ks[64*KSTR];    // 17.0 KB (Ps aliases this)
  __shared__ __align__(16) uint16_t Vs[128*VSTR];   // 18.0 KB
  uint16_t* Ps = Ks;  // [q=64][key=64] stride VSTR — fits in Ks region

  const int tid  = threadIdx.x;
  const int wave = tid >> 6;
  const int lane = tid & 63;
  const int fr = lane & 15;
  const int g  = lane >> 4;
  const int fo = g * 8;
  const int bh = blockIdx.y;
  const int b = bh >> 5, h = bh & 31;
  const int kvh = h >> 2;   // GQA: 4 Q-heads per KV-head

  uint16_t*       Qh = Q  + (size_t)b*SEQ*HIDDEN + (size_t)h*HD;
  const uint16_t* Kp = K  + (size_t)b*SEQ*KVDIM  + (size_t)kvh*HD;
  const uint16_t* Vp = Vt + ((size_t)b*NKVH + kvh)*HD*SEQ;

  #pragma unroll
  for (int pass = 0; pass < 2; ++pass) {
    const int qt = pass ? (31 - (int)blockIdx.x) : (int)blockIdx.x;
    const int q0 = qt * 64;
    const int qrow_base = q0 + wave*16 + g*4;   // + r = this lane's softmax rows

    // Q fragments (A-layout): wave's 16 q-rows, d=0..127
    bf16x8 qf[4];
    #pragma unroll
    for (int ks = 0; ks < 4; ++ks)
      qf[ks] = ld_frag(Qh + (size_t)(q0 + wave*16 + fr)*HIDDEN + ks*32 + fo);

    float m_i[4], l_i[4];
    f32x4 oacc[8] = {};
    #pragma unroll
    for (int r = 0; r < 4; ++r) { m_i[r] = NEG_BIG; l_i[r] = 0.f; }

    const int nkt = qt + 1;   // causal: keys up to q0+63
    for (int kt = 0; kt < nkt; ++kt) {
      const int k0 = kt * 64;
      __syncthreads();   // prev iter's Vs/Ps reads done before restaging
      #pragma unroll
      for (int i = 0; i < 4; ++i) {
        int gi = tid + i*256;                    // 0..1023
        int kr = gi >> 4, kc = (gi & 15) * 8;    // Ks: 64 x 128
        *(bf16x8*)&Ks[kr*KSTR + kc] = *(const bf16x8*)(Kp + (size_t)(k0 + kr)*KVDIM + kc);
        int vr = gi >> 3, vc = (gi & 7) * 8;     // Vs: 128 x 64
        *(bf16x8*)&Vs[vr*VSTR + vc] = *(const bf16x8*)(Vp + (size_t)vr*SEQ + k0 + vc);
      }
      __syncthreads();

      // S = Q K^T   (16 q-rows x 64 keys per wave)
      f32x4 sacc[4] = {};
      #pragma unroll
      for (int ks = 0; ks < 4; ++ks) {
        bf16x8 bk[4];
        #pragma unroll
        for (int j = 0; j < 4; ++j) bk[j] = ld_frag(&Ks[(j*16 + fr)*KSTR + ks*32 + fo]);
        #pragma unroll
        for (int j = 0; j < 4; ++j) sacc[j] = MFMA_BF16(qf[ks], bk[j], sacc[j]);
      }

      // scale + causal mask + online softmax (row spans 16 lanes of this g-group)
      const bool diag = (kt == qt);
      #pragma unroll
      for (int r = 0; r < 4; ++r) {
        float vals[4];
        #pragma unroll
        for (int j = 0; j < 4; ++j) {
          float v = sacc[j][r] * 0.08838834764831845f;  // 1/sqrt(128)
          if (diag && (k0 + j*16 + fr > qrow_base + r)) v = NEG_BIG;
          vals[j] = v;
        }
        float mt = fmaxf(fmaxf(vals[0], vals[1]), fmaxf(vals[2], vals[3]));
        #pragma unroll
        for (int off = 1; off < 16; off <<= 1) mt = fmaxf(mt, __shfl_xor(mt, off, 64));
        float mn = fmaxf(m_i[r], mt);
        float alpha = __expf(fminf(m_i[r] - mn, 0.f));
        float lt = 0.f;
        #pragma unroll
        for (int j = 0; j < 4; ++j) {
          float p = __expf(fminf(vals[j] - mn, 0.f));
          sacc[j][r] = p;
          lt += p;
        }
        #pragma unroll
        for (int off = 1; off < 16; off <<= 1) lt += __shfl_xor(lt, off, 64);
        m_i[r] = mn;
        l_i[r] = l_i[r]*alpha + lt;
        #pragma unroll
        for (int n = 0; n < 8; ++n) oacc[n][r] *= alpha;
      }

      __syncthreads();   // all waves finished reading Ks before P overwrites it

      // P (C-layout) -> Ps (A-layout source); wave writes/reads only its strip
      #pragma unroll
      for (int j = 0; j < 4; ++j)
        #pragma unroll
        for (int r = 0; r < 4; ++r)
          Ps[(wave*16 + g*4 + r)*VSTR + j*16 + fr] = f32_to_bf16(sacc[j][r]);

      // O += P * V   (no barrier: own-strip Ps; Vs stable since staging)
      #pragma unroll
      for (int ks = 0; ks < 2; ++ks) {
        bf16x8 ap = ld_frag(&Ps[(wave*16 + fr)*VSTR + ks*32 + fo]);
        #pragma unroll
        for (int half = 0; half < 2; ++half) {
          bf16x8 bv[4];
          #pragma unroll
          for (int n = 0; n < 4; ++n)
            bv[n] = ld_frag(&Vs[((half*4 + n)*16 + fr)*VSTR + ks*32 + fo]);
          #pragma unroll
          for (int n = 0; n < 4; ++n)
            oacc[half*4 + n] = MFMA_BF16(ap, bv[n], oacc[half*4 + n]);
        }
      }
    }

    // epilogue: O over Q in-place (only this block's rows)
    #pragma unroll
    for (int r = 0; r < 4; ++r) {
      float inv_l = 1.0f / l_i[r];
      #pragma unroll
      for (int n = 0; n < 8; ++n)
        Qh[(size_t)(qrow_base + r)*HIDDEN + n*16 + fr] = f32_to_bf16(oacc[n][r] * inv_l);
    }
    __syncthreads();   // LDS/Q safe before next pass
  }
}

// ============================================================================
extern "C" void kernel_launch(void* const* d_in, const int* in_sizes, int n_in,
                              void* d_out, int out_size, void* d_ws, size_t ws_size,
                              hipStream_t stream)
{
  (void)in_sizes; (void)n_in; (void)out_size; (void)ws_size;
  const float* hidden = (const float*)d_in[0];   // fp32 per reference
  const float* wq = (const float*)d_in[2];
  const float* wk = (const float*)d_in[3];
  const float* wv = (const float*)d_in[4];
  const float* wo = (const float*)d_in[5];
  float* out = (float*)d_out;                    // fp32 per reference output

  // bf16 workspace with aliasing (~134 MB):
  //  R0: Xb (until qkv) -> Wob ; R1: Wqb (until qkv) -> Vt
  uint16_t* R0 = (uint16_t*)d_ws;                         // 16.78M elems
  uint16_t* R1 = R0 + (size_t)HIDDEN*HIDDEN;              // 16.78M
  uint16_t* R2 = R1 + (size_t)HIDDEN*HIDDEN;              //  4.19M
  uint16_t* R3 = R2 + (size_t)KVDIM*HIDDEN;               //  4.19M
  uint16_t* Qb = R3 + (size_t)KVDIM*HIDDEN;               // 16.78M
  uint16_t* Kb = Qb + (size_t)TOKENS*HIDDEN;              //  4.19M
  uint16_t* Vb = Kb + (size_t)TOKENS*KVDIM;               //  4.19M

  dim3 blk(256);
  cvt_all<<<dim3(20480), blk, 0, stream>>>(hidden, wq, wk, wv, R0, R1, R2, R3);
  qkv_gemm<<<dim3(48, TOKENS/128), blk, 0, stream>>>(R0, R1, R2, R3, Qb, Kb, Vb);
  rope_kernel<<<dim3(TOKENS*(NH+NKVH)*64/256), blk, 0, stream>>>(Qb, Kb);
  cvt_one<<<dim3(HIDDEN*HIDDEN/8/256), blk, 0, stream>>>(wo, R0);   // Wo -> R0 (Xb dead)
  transpose_v<<<dim3(SEQ/64, HD/64, BATCH*NKVH), blk, 0, stream>>>(Vb, R1); // Vt -> R1
  flash_attn<<<dim3(16, BATCH*NH), blk, 0, stream>>>(Qb, Kb, R1);
  out_gemm<<<dim3(HIDDEN/128, TOKENS/128), blk, 0, stream>>>(Qb, R0, out, HIDDEN, HIDDEN);
}